// Round 1
// baseline (15580.275 us; speedup 1.0000x reference)
//
#include <hip/hip_runtime.h>

// Problem constants (match reference)
#define Bx   256
#define Tx   512
#define LAT  128
#define CND  32
#define HIDN 512
#define OUTD 64
// K layout for the fused gate GEMM: [prev(64) | cond(32) | h(512)] = 608
// chunks of 32: 0,1 = prev, 2 = cond, 3..18 = h   (19 chunks)

__device__ __forceinline__ float sigmoidf_(float x) {
    return 1.0f / (1.0f + __expf(-x));
}

// ---------------------------------------------------------------------------
// init: h0 = latent @ W_lh^T + b_lh ; c0 likewise ; out[:,0,:] = 1
// grid 256 (one block per batch row), 256 threads (2 hidden cols each)
// ---------------------------------------------------------------------------
__global__ __launch_bounds__(256) void init_kernel(
    const float* __restrict__ latent, const float* __restrict__ W_lh,
    const float* __restrict__ b_lh,   const float* __restrict__ W_lc,
    const float* __restrict__ b_lc,   float* __restrict__ h0,
    float* __restrict__ c0,           float* __restrict__ out)
{
    const int b = blockIdx.x;
    const float4* lat4 = reinterpret_cast<const float4*>(latent + b * LAT);
#pragma unroll
    for (int jj = 0; jj < 2; ++jj) {
        const int j = threadIdx.x + jj * 256;
        const float4* wh4 = reinterpret_cast<const float4*>(W_lh + j * LAT);
        const float4* wc4 = reinterpret_cast<const float4*>(W_lc + j * LAT);
        float sh = 0.f, sc = 0.f;
#pragma unroll 8
        for (int k = 0; k < LAT / 4; ++k) {
            float4 l = lat4[k], a = wh4[k], c = wc4[k];
            sh += l.x * a.x + l.y * a.y + l.z * a.z + l.w * a.w;
            sc += l.x * c.x + l.y * c.y + l.z * c.z + l.w * c.w;
        }
        h0[b * HIDN + j] = sh + b_lh[j];
        c0[b * HIDN + j] = sc + b_lc[j];
    }
    if (threadIdx.x < OUTD) out[b * (Tx * OUTD) + threadIdx.x] = 1.0f;
}

// ---------------------------------------------------------------------------
// step kernel, launched once per time step j = 0..511.
//  j in 0..510 : gates from [x_j, h_{j-1}], update c, write h_j -> hnext
//  j in 1..511 : project h_{j-1} -> out[:, j, :]
// grid 256 = 4 batch-slices(64 rows) x 64 hidden-slices(8 units = 32 gatecols)
// block 256 threads: thread = rr(0..31)*8 + u(0..7); tile 2 rows x 4 gates
// ---------------------------------------------------------------------------
__global__ __launch_bounds__(256) void step_kernel(
    int j,
    const float* __restrict__ target, const float* __restrict__ cond,
    const float* __restrict__ hprev,  float* __restrict__ hnext,
    float* __restrict__ cbuf,
    const float* __restrict__ W_ih,   const float* __restrict__ W_hh,
    const float* __restrict__ b_ih,   const float* __restrict__ b_hh,
    const float* __restrict__ W_out,  const float* __restrict__ b_out,
    float* __restrict__ out)
{
    const int tid = threadIdx.x;
    const int bs  = blockIdx.x >> 6;   // batch slice 0..3
    const int hs  = blockIdx.x & 63;   // hidden slice 0..63  (xcd = hs%8)

    // ---- output projection: out[:, j, hs] = W_out[hs] . h_{j-1} + b_out[hs]
    if (j >= 1) {
        const int r = tid >> 2, q = tid & 3;       // 64 rows x 4 k-quarters
        const int gb = bs * 64 + r;
        const float4* h4 = reinterpret_cast<const float4*>(hprev + gb * HIDN + q * 128);
        const float4* w4 = reinterpret_cast<const float4*>(W_out + hs * HIDN + q * 128);
        float p = 0.f;
#pragma unroll 8
        for (int k = 0; k < 32; ++k) {
            float4 h = h4[k], w = w4[k];
            p += h.x * w.x + h.y * w.y + h.z * w.z + h.w * w.w;
        }
        p += __shfl_xor(p, 1);
        p += __shfl_xor(p, 2);
        if (q == 0) out[gb * (Tx * OUTD) + j * OUTD + hs] = p + b_out[hs];
    }
    if (j >= 511) return;   // uniform: last launch is projection-only

    // ---- fused gate GEMM: gates[64r x 32c] = [x_j,h] @ Wslice^T -----------
    __shared__ float As[2][64][36];   // +4 pad: conflict-free f4 reads
    __shared__ float Ws[2][32][36];

    const int u  = tid & 7;           // hidden unit within slice
    const int rr = tid >> 3;          // row-pair 0..31
    const int r0 = rr * 2, r1 = r0 + 1;

    // staging decomposition (coalesced: consecutive tid -> consecutive f4)
    const int ar0 = tid >> 3;         // A row for f4 #0 (rows 0..31); #1 adds 32
    const int akq = tid & 7;          // f4 index within 32-wide chunk
    const int wc  = tid >> 3;         // W LDS row 0..31
    const int wg  = wc >> 3, wul = wc & 7;
    const int wn  = wg * 512 + hs * 8 + wul;   // global gate-row index

    auto loadA = [&](int chunk, int r) -> float4 {
        const int gb = bs * 64 + r;
        const int kk = akq * 4;
        if (chunk < 2) {
            if (j == 0) return make_float4(1.f, 1.f, 1.f, 1.f);   // SOH row
            const int k = chunk * 32 + kk;                         // 0..63
            return *reinterpret_cast<const float4*>(target + (gb * Tx + j) * OUTD + k);
        } else if (chunk == 2) {
            return *reinterpret_cast<const float4*>(cond + gb * CND + kk);
        } else {
            return *reinterpret_cast<const float4*>(hprev + gb * HIDN + (chunk - 3) * 32 + kk);
        }
    };
    auto loadW = [&](int chunk) -> float4 {
        const int kk = akq * 4;
        if (chunk < 3)
            return *reinterpret_cast<const float4*>(W_ih + wn * 96 + chunk * 32 + kk);
        else
            return *reinterpret_cast<const float4*>(W_hh + wn * HIDN + (chunk - 3) * 32 + kk);
    };
    auto storeStage = [&](int bi, const float4& a0v, const float4& a1v, const float4& wv) {
        *reinterpret_cast<float4*>(&As[bi][ar0][akq * 4])      = a0v;
        *reinterpret_cast<float4*>(&As[bi][ar0 + 32][akq * 4]) = a1v;
        *reinterpret_cast<float4*>(&Ws[bi][wc][akq * 4])       = wv;
    };

    // software pipeline: LDS double-buffer + 2-deep register prefetch
    float4 curA0 = loadA(0, ar0);
    float4 curA1 = loadA(0, ar0 + 32);
    float4 curW  = loadW(0);
    storeStage(0, curA0, curA1, curW);
    curA0 = loadA(1, ar0);
    curA1 = loadA(1, ar0 + 32);
    curW  = loadW(1);
    __syncthreads();

    float acc0[4] = {0.f, 0.f, 0.f, 0.f};
    float acc1[4] = {0.f, 0.f, 0.f, 0.f};

    for (int i = 0; i < 19; ++i) {
        float4 nA0 = {}, nA1 = {}, nW = {};
        if (i + 2 <= 18) {                 // issue next-next chunk loads early
            nA0 = loadA(i + 2, ar0);
            nA1 = loadA(i + 2, ar0 + 32);
            nW  = loadW(i + 2);
        }
        const int bi = i & 1;
#pragma unroll
        for (int kq = 0; kq < 8; ++kq) {
            float4 a0 = *reinterpret_cast<const float4*>(&As[bi][r0][kq * 4]);
            float4 a1 = *reinterpret_cast<const float4*>(&As[bi][r1][kq * 4]);
#pragma unroll
            for (int g = 0; g < 4; ++g) {
                float4 w = *reinterpret_cast<const float4*>(&Ws[bi][g * 8 + u][kq * 4]);
                acc0[g] += a0.x * w.x + a0.y * w.y + a0.z * w.z + a0.w * w.w;
                acc1[g] += a1.x * w.x + a1.y * w.y + a1.z * w.z + a1.w * w.w;
            }
        }
        if (i + 1 <= 18) storeStage((i + 1) & 1, curA0, curA1, curW);
        curA0 = nA0; curA1 = nA1; curW = nW;
        __syncthreads();
    }

    // ---- epilogue: bias + LSTM cell update --------------------------------
    const int hu = hs * 8 + u;
    float bias[4];
#pragma unroll
    for (int g = 0; g < 4; ++g) {
        const int n = g * 512 + hu;
        bias[g] = b_ih[n] + b_hh[n];
    }
    const int gb0 = bs * 64 + r0;
    {
        float ig = sigmoidf_(acc0[0] + bias[0]);
        float fg = sigmoidf_(acc0[1] + bias[1]);
        float gg = tanhf    (acc0[2] + bias[2]);
        float og = sigmoidf_(acc0[3] + bias[3]);
        float c_old = cbuf[gb0 * HIDN + hu];
        float c_new = fg * c_old + ig * gg;
        cbuf [gb0 * HIDN + hu] = c_new;
        hnext[gb0 * HIDN + hu] = og * tanhf(c_new);
    }
    {
        float ig = sigmoidf_(acc1[0] + bias[0]);
        float fg = sigmoidf_(acc1[1] + bias[1]);
        float gg = tanhf    (acc1[2] + bias[2]);
        float og = sigmoidf_(acc1[3] + bias[3]);
        float c_old = cbuf[(gb0 + 1) * HIDN + hu];
        float c_new = fg * c_old + ig * gg;
        cbuf [(gb0 + 1) * HIDN + hu] = c_new;
        hnext[(gb0 + 1) * HIDN + hu] = og * tanhf(c_new);
    }
}

// ---------------------------------------------------------------------------
extern "C" void kernel_launch(void* const* d_in, const int* in_sizes, int n_in,
                              void* d_out, int out_size, void* d_ws, size_t ws_size,
                              hipStream_t stream) {
    const float* latent = (const float*)d_in[0];
    const float* cond   = (const float*)d_in[1];
    const float* target = (const float*)d_in[2];
    const float* W_lh   = (const float*)d_in[3];
    const float* b_lh   = (const float*)d_in[4];
    const float* W_lc   = (const float*)d_in[5];
    const float* b_lc   = (const float*)d_in[6];
    const float* W_ih   = (const float*)d_in[7];
    const float* W_hh   = (const float*)d_in[8];
    const float* b_ih   = (const float*)d_in[9];
    const float* b_hh   = (const float*)d_in[10];
    const float* W_out  = (const float*)d_in[11];
    const float* b_out  = (const float*)d_in[12];
    // d_in[13] = output_lengths (all == T) -- unused

    float* out = (float*)d_out;
    float* ws  = (float*)d_ws;
    // ws layout (floats): hbuf0 [256][512] | hbuf1 [256][512] | cbuf [256][512]
    float* hbuf0 = ws;
    float* hbuf1 = ws + Bx * HIDN;
    float* cbuf  = ws + 2 * Bx * HIDN;   // total 1.5 MB

    hipLaunchKernelGGL(init_kernel, dim3(Bx), dim3(256), 0, stream,
                       latent, W_lh, b_lh, W_lc, b_lc, hbuf0, cbuf, out);

    for (int j = 0; j <= 511; ++j) {
        float* hp = (j & 1) ? hbuf1 : hbuf0;   // holds h_{j-1}
        float* hn = (j & 1) ? hbuf0 : hbuf1;   // receives h_j
        hipLaunchKernelGGL(step_kernel, dim3(256), dim3(256), 0, stream,
                           j, target, cond, hp, hn, cbuf,
                           W_ih, W_hh, b_ih, b_hh, W_out, b_out, out);
    }
}

// Round 2
// 6711.266 us; speedup vs baseline: 2.3215x; 2.3215x over previous
//
#include <hip/hip_runtime.h>

// Problem constants
#define Bx    256
#define Tx    512
#define LAT   128
#define CND   32
#define HIDN  512
#define OUTD  64
#define KD    608           // K = 64(prev) + 32(cond) + 512(h)
#define KP    616           // padded LDS/Wg stride in bf16 elems (stride 308 dw -> 2-way banks, free)
#define ROWS  32            // batch rows per step-block
#define NCOLS 32            // gate cols per step-block (8 units x 4 gates)

typedef unsigned short u16;
typedef unsigned int   u32;
typedef short s16x8 __attribute__((ext_vector_type(8)));
typedef unsigned short u16x8 __attribute__((ext_vector_type(8)));
typedef float f32x4 __attribute__((ext_vector_type(4)));

// ws layout (bytes)
#define WG_SLICE (NCOLS * KP * 2)            // 39424 B per hidden slice
#define WG_OFF   0
#define WG_BYTES (64 * WG_SLICE)             // 2523136
#define H0_OFF   (WG_BYTES)                  // h double-buffer, bf16 bits
#define H1_OFF   (H0_OFF + Bx * HIDN * 2)
#define CB_OFF   (H1_OFF + Bx * HIDN * 2)    // c state, fp32
#define BS_OFF   (CB_OFF + Bx * HIDN * 4)    // b_ih+b_hh, fp32 [2048]

__device__ __forceinline__ float sigmoidf_(float x) { return 1.0f / (1.0f + __expf(-x)); }

__device__ __forceinline__ u16 f2bf(float f) {          // RNE fp32 -> bf16 bits
    union { float f; u32 u; } v; v.f = f;
    u32 r = (v.u + 0x7FFFu + ((v.u >> 16) & 1u)) >> 16;
    return (u16)r;
}
__device__ __forceinline__ float bf2f(u16 s) {
    union { u32 u; float f; } v; v.u = ((u32)s) << 16;
    return v.f;
}
__device__ __forceinline__ void gl_lds16(const void* g, void* l) {
    __builtin_amdgcn_global_load_lds(
        (const __attribute__((address_space(1))) unsigned int*)g,
        (__attribute__((address_space(3))) unsigned int*)l, 16, 0, 0);
}

// ---------------------------------------------------------------------------
// prep: gather [W_ih | W_hh] -> bf16 Wg[hs][col=g*8+u][k(pad 616)]; bsum = b_ih+b_hh
// ---------------------------------------------------------------------------
__global__ __launch_bounds__(256) void prep_w(
    const float* __restrict__ W_ih, const float* __restrict__ W_hh,
    const float* __restrict__ b_ih, const float* __restrict__ b_hh,
    u16* __restrict__ Wg, float* __restrict__ bsum)
{
    const int idx = blockIdx.x * 256 + threadIdx.x;
    if (idx < 64 * NCOLS * KD) {
        const int k   = idx % KD;
        const int t   = idx / KD;
        const int col = t % NCOLS;
        const int hs  = t / NCOLS;
        const int g = col >> 3, u = col & 7;
        const int n = g * HIDN + hs * 8 + u;
        const float v = (k < 96) ? W_ih[n * 96 + k] : W_hh[n * HIDN + (k - 96)];
        Wg[(hs * NCOLS + col) * KP + k] = f2bf(v);
    }
    if (idx < 4 * HIDN) bsum[idx] = b_ih[idx] + b_hh[idx];
}

// ---------------------------------------------------------------------------
// init: h0 (bf16) = latent @ W_lh^T + b_lh ; c0 (fp32) ; out[:,0,:] = 1
// ---------------------------------------------------------------------------
__global__ __launch_bounds__(256) void init_kernel(
    const float* __restrict__ latent, const float* __restrict__ W_lh,
    const float* __restrict__ b_lh,   const float* __restrict__ W_lc,
    const float* __restrict__ b_lc,   u16* __restrict__ h0,
    float* __restrict__ c0,           float* __restrict__ out)
{
    const int b = blockIdx.x;
    const float4* lat4 = reinterpret_cast<const float4*>(latent + b * LAT);
#pragma unroll
    for (int jj = 0; jj < 2; ++jj) {
        const int j = threadIdx.x + jj * 256;
        const float4* wh4 = reinterpret_cast<const float4*>(W_lh + j * LAT);
        const float4* wc4 = reinterpret_cast<const float4*>(W_lc + j * LAT);
        float sh = 0.f, sc = 0.f;
#pragma unroll 8
        for (int k = 0; k < LAT / 4; ++k) {
            float4 l = lat4[k], a = wh4[k], c = wc4[k];
            sh += l.x * a.x + l.y * a.y + l.z * a.z + l.w * a.w;
            sc += l.x * c.x + l.y * c.y + l.z * c.z + l.w * c.w;
        }
        h0[b * HIDN + j] = f2bf(sh + b_lh[j]);
        c0[b * HIDN + j] = sc + b_lc[j];
    }
    if (threadIdx.x < OUTD) out[b * (Tx * OUTD) + threadIdx.x] = 1.0f;
}

// ---------------------------------------------------------------------------
// step j: (j>=1) project h_{j-1} -> out[:,j,:]; (j<=510) MFMA gate GEMM + cell
// grid 512 = 8 batch-slices(32 rows) x 64 hidden-slices(8 units)
// LDS: A[32][616]bf16 + W[32][616]bf16 (+tail) = 80.4 KB -> 2 blocks/CU
// ---------------------------------------------------------------------------
__global__ __launch_bounds__(256, 2) void step_kernel(
    int j,
    const float* __restrict__ target, const float* __restrict__ cond,
    const u16* __restrict__ hprev,    u16* __restrict__ hnext,
    float* __restrict__ cbuf,         const u16* __restrict__ Wg,
    const float* __restrict__ bsum,
    const float* __restrict__ W_out,  const float* __restrict__ b_out,
    float* __restrict__ out)
{
    const int tid  = threadIdx.x;
    const int bs   = blockIdx.x >> 6;   // 0..7
    const int hs   = blockIdx.x & 63;   // 0..63 (XCD = hs % 8)
    const int w    = tid >> 6;
    const int lane = tid & 63;

    // ---- output projection: out[:, j, hs] = W_out[hs] . h_{j-1} + b_out[hs]
    if (j >= 1) {
        const int r = tid >> 3, q = tid & 7;
        const int gb = bs * ROWS + r;
        const u16*   hp = hprev + gb * HIDN + q * 64;
        const float* wo = W_out + hs * HIDN + q * 64;
        float p = 0.f;
#pragma unroll
        for (int i = 0; i < 8; ++i) {
            u16x8 hv = *reinterpret_cast<const u16x8*>(hp + i * 8);
            float4 w0 = *reinterpret_cast<const float4*>(wo + i * 8);
            float4 w1 = *reinterpret_cast<const float4*>(wo + i * 8 + 4);
            p += bf2f(hv[0]) * w0.x + bf2f(hv[1]) * w0.y + bf2f(hv[2]) * w0.z + bf2f(hv[3]) * w0.w
               + bf2f(hv[4]) * w1.x + bf2f(hv[5]) * w1.y + bf2f(hv[6]) * w1.z + bf2f(hv[7]) * w1.w;
        }
        p += __shfl_xor(p, 1); p += __shfl_xor(p, 2); p += __shfl_xor(p, 4);
        if (q == 0) out[gb * (Tx * OUTD) + j * OUTD + hs] = p + b_out[hs];
    }
    if (j >= Tx - 1) return;            // last launch: projection only (uniform)

    __shared__ __align__(16) char smem[2 * ROWS * KP * 2 + 1536];
    u16*   As   = (u16*)smem;                          // [32][616]
    u16*   Ws   = (u16*)(smem + ROWS * KP * 2);        // [32][616] (+tail pad)
    float* gbuf = (float*)smem;                        // [32][36], aliased after MFMA

    // ---- stage A x-part (k 0..95): target prev (ones at j==0) + cond, fp32->bf16
    {
        const int r = tid >> 3, t8 = tid & 7;
        const int gb = bs * ROWS + r;
        const float* tg = target + (gb * Tx + j) * OUTD;
#pragma unroll
        for (int m = 0; m < 12; ++m) {
            const int k = t8 * 12 + m;
            float v;
            if (k < OUTD) v = (j == 0) ? 1.0f : tg[k];
            else          v = cond[gb * CND + (k - OUTD)];
            As[r * KP + k] = f2bf(v);
        }
    }
    // ---- stage A h-part (k 96..607): one global_load_lds dwordx4 per row per wave
#pragma unroll
    for (int it = 0; it < 8; ++it) {
        const int rr = w + it * 4;
        gl_lds16(hprev + (bs * ROWS + rr) * HIDN + lane * 8, (void*)(As + rr * KP + 96));
    }
    // ---- stage W slice (contiguous 39424 B, rounded to 40960 into tail pad)
    {
        const u16* wsrc = Wg + hs * (NCOLS * KP);
#pragma unroll
        for (int it = 0; it < 10; ++it) {
            const int seg = it * 256 + w * 64;
            gl_lds16(wsrc + seg * 8 + lane * 8, (void*)(Ws + seg * 8));
        }
    }
    __syncthreads();

    // ---- MFMA: 4 waves x one 16x16 tile, K = 19 chunks of 32
    const int mrow = ((w & 1) << 4) + (lane & 15);
    const int ncol = ((w >> 1) << 4) + (lane & 15);
    const int kq   = (lane >> 4) << 3;
    const u16* ap = As + mrow * KP + kq;
    const u16* bp = Ws + ncol * KP + kq;
    f32x4 acc = {0.f, 0.f, 0.f, 0.f};
#pragma unroll
    for (int ck = 0; ck < 19; ++ck) {
        s16x8 a = *reinterpret_cast<const s16x8*>(ap + ck * 32);
        s16x8 b = *reinterpret_cast<const s16x8*>(bp + ck * 32);
        acc = __builtin_amdgcn_mfma_f32_16x16x32_bf16(a, b, acc, 0, 0, 0);
    }
    __syncthreads();                    // A reads done before aliasing gbuf over As

    // ---- scatter gates (C/D layout: col=lane&15, row=quad*4+reg) to gbuf
    {
        const int row0 = ((w & 1) << 4) + ((lane >> 4) << 2);
#pragma unroll
        for (int t = 0; t < 4; ++t) gbuf[(row0 + t) * 36 + ncol] = acc[t];
    }
    __syncthreads();

    // ---- cell update: thread = (row r, unit u)
    {
        const int r = tid >> 3, u = tid & 7;
        const int gb = bs * ROWS + r, hu = hs * 8 + u;
        const float gi = gbuf[r * 36 +      u] + bsum[0 * HIDN + hu];
        const float gf = gbuf[r * 36 +  8 + u] + bsum[1 * HIDN + hu];
        const float gg = gbuf[r * 36 + 16 + u] + bsum[2 * HIDN + hu];
        const float go = gbuf[r * 36 + 24 + u] + bsum[3 * HIDN + hu];
        const float ig = sigmoidf_(gi), fg = sigmoidf_(gf);
        const float gt = tanhf(gg),     og = sigmoidf_(go);
        const float co = cbuf[gb * HIDN + hu];
        const float cn = fg * co + ig * gt;
        cbuf[gb * HIDN + hu]  = cn;
        hnext[gb * HIDN + hu] = f2bf(og * tanhf(cn));
    }
}

// ---------------------------------------------------------------------------
extern "C" void kernel_launch(void* const* d_in, const int* in_sizes, int n_in,
                              void* d_out, int out_size, void* d_ws, size_t ws_size,
                              hipStream_t stream) {
    const float* latent = (const float*)d_in[0];
    const float* cond   = (const float*)d_in[1];
    const float* target = (const float*)d_in[2];
    const float* W_lh   = (const float*)d_in[3];
    const float* b_lh   = (const float*)d_in[4];
    const float* W_lc   = (const float*)d_in[5];
    const float* b_lc   = (const float*)d_in[6];
    const float* W_ih   = (const float*)d_in[7];
    const float* W_hh   = (const float*)d_in[8];
    const float* b_ih   = (const float*)d_in[9];
    const float* b_hh   = (const float*)d_in[10];
    const float* W_out  = (const float*)d_in[11];
    const float* b_out  = (const float*)d_in[12];

    float* out = (float*)d_out;
    char*  ws  = (char*)d_ws;
    u16*   Wg    = (u16*)(ws + WG_OFF);
    u16*   hbuf0 = (u16*)(ws + H0_OFF);
    u16*   hbuf1 = (u16*)(ws + H1_OFF);
    float* cbuf  = (float*)(ws + CB_OFF);
    float* bsum  = (float*)(ws + BS_OFF);

    hipLaunchKernelGGL(prep_w, dim3(4864), dim3(256), 0, stream,
                       W_ih, W_hh, b_ih, b_hh, Wg, bsum);
    hipLaunchKernelGGL(init_kernel, dim3(Bx), dim3(256), 0, stream,
                       latent, W_lh, b_lh, W_lc, b_lc, hbuf0, cbuf, out);

    for (int j = 0; j < Tx; ++j) {
        u16* hp = (j & 1) ? hbuf1 : hbuf0;   // h_{j-1}
        u16* hn = (j & 1) ? hbuf0 : hbuf1;   // h_j
        hipLaunchKernelGGL(step_kernel, dim3(512), dim3(256), 0, stream,
                           j, target, cond, hp, hn, cbuf,
                           Wg, bsum, W_out, b_out, out);
    }
}